// Round 5
// baseline (224.500 us; speedup 1.0000x reference)
//
#include <hip/hip_runtime.h>

#define HBV_B  1024
#define HBV_NZ 1e-5f
#define SBUF   (30 * 64)       // one 30-step superchunk buffer (64 lanes)

// ---------------------------------------------------------------------------
// R12b = R12 resubmitted verbatim (R4 bench was an infra failure: container
// acquire flake, no kernel verdict; diff vs R11 is straight-line math only,
// no hang mechanism).
// R12 = R11 (solo-SIMD soil, 256x256, 30-chunk/69-barrier machine, ET clamp
// fold) + capillary med3 fold: chain 4T+7V -> 4T+6V.
//  - Model (validated R11): wall = 2000 x soil-chain dep latency on a quiet
//    SIMD; fitted trans dep ~40 cyc, VALU dep ~6-7 cyc (199 cyc/step @ 4T+7V).
//  - med3 fold: SM3 = min(SM1,FC)*c1 + CSLZ = clamp(SM1*c1+CSLZ, lo, hi),
//    knee K = FC*c1+CSLZ; (lo,hi) = c1>=0 ? (-MAX,K) : (K,+MAX) (affine map
//    direction flips with sign of c1). SM3a folds rain: fma(-rt*c1, sw,
//    (SM+rt)*c1+CSLZ); the addend is a side path off SM that finishes inside
//    the log->fma->exp front (~86 cyc). sw->fma->med3->log = 2 V levels
//    (was fma->min->fma = 3). SM1/SM2 recomputed off-chain for SUZ/SLZ/Q.
//  - Chain: log,fma,exp | fma,med3 | log,fma,exp | fma,max = 4T+6V ~ 196 cyc.
// Roles: wv0 soil (SIMD0, solo), wv1 route, wv2 snow, wv3 idle; 1 block/CU
// via 36 KB dynamic-LDS pad (46+36 > 80 KB).
// Phase machine (69 barriers/wave), superchunks sc=0..66 (sc66 = 20 steps):
//   phase p: snow sc p (p<=66) | soil sc p-1 (1<=p<=67) | route sc p-2
//   (2<=p<=68). Buffer parity = sc&1. Sub-blocks of 15 keep FIR ring aligned.
// ---------------------------------------------------------------------------

struct F3 { float x, y, z; };

#define DPP_ADD_ROR(x, ctrl) do {                                              \
    int _r = __builtin_amdgcn_update_dpp(0, __float_as_int(x),                 \
                                         (ctrl), 0xF, 0xF, true);              \
    (x) += __int_as_float(_r);                                                 \
} while (0)

#define HBV_FLTMAX 3.402823466e+38f

// ---- soil step: hw trans chain, 4T + 6V deep ------------------------------
#define SOIL_STEP(s, rt_, pet_, qdst) do {                                     \
    float rt   = (rt_);                                                        \
    float PETm = (pet_);                                                       \
    /* off-chain prep (ready before sw resolves) */                            \
    float CSLZ = parC * SLZ;                                                   \
    float c1   = __builtin_fmaf(-CSLZ, invFC, 1.0f);                           \
    float Kc   = __builtin_fmaf(parFC, c1, CSLZ);                              \
    float lo   = (c1 >= 0.0f) ? -HBV_FLTMAX : Kc;                              \
    float hi   = (c1 >= 0.0f) ? Kc : HBV_FLTMAX;                               \
    float nrtc1 = -rt * c1;                                                    \
    float SMrt = SM + rt;                                                      \
    float Ac   = __builtin_fmaf(SMrt, c1, CSLZ);    /* side path off SM */     \
    /* ---- cross-step critical chain ---- */                                  \
    float lSM = __builtin_amdgcn_logf(SM);                                     \
    float esw = __builtin_fmaf(parBETA, lSM, nBlogFC);                         \
    float swr = __builtin_amdgcn_exp2f(esw);                                   \
    float sw  = fminf(fmaxf(swr, 0.0f), 1.0f);   /* -> v_exp clamp mod */      \
    float SM3a = __builtin_fmaf(nrtc1, sw, Ac);                                \
    float SM3  = __builtin_amdgcn_fmed3f(SM3a, lo, hi);                        \
    float lS3 = __builtin_amdgcn_logf(SM3);                                    \
    float eef = __builtin_fmaf(parBETAET, lS3, nBEloglpfc);                    \
    float efr = __builtin_amdgcn_exp2f(eef);                                   \
    float ef  = fminf(fmaxf(efr, 0.0f), 1.0f);   /* -> v_exp clamp mod */      \
    SM = fmaxf(__builtin_fmaf(-PETm, ef, SM3), HBV_NZ);                        \
    /* ---- off-chain: SM1/SM2 recompute + SUZ/SLZ/Q ---- */                   \
    float SM1 = __builtin_fmaf(-rt, sw, SMrt);                                 \
    float SM2 = fminf(SM1, parFC);                                             \
    float U_ = __builtin_fmaf(rt, sw, SM1 - SM2);   /* recharge+excess */      \
    float S_ = SUZ + U_;                                                       \
    float P_ = fminf(S_, parPERC);                                             \
    float A_ = S_ - P_;                                                        \
    float B_ = fminf(A_, __builtin_fmaf(K0c, A_, K0UZL));                      \
    SUZ = K1c * B_;                                                            \
    float L_ = SLZ - (SM3 - SM2) + P_;                                         \
    SLZ = K2c * L_;                                                            \
    (qdst)[(s) * 64] = __builtin_fmaf(parK2, L_, A_ - SUZ);                    \
} while (0)

// One 15-or-5-step sub-block: stage LDS -> registers, run steps.
#define SOIL_HALF(nn, ofs) do {                                                \
    const float* rs = &rtS[(ofs)];                                             \
    const float* es = &petS[(ofs)];                                            \
    float* qd = &qS[(ofs)];                                                    \
    float rr[15], pv[15];                                                      \
    _Pragma("unroll")                                                          \
    for (int k_ = 0; k_ < (nn); ++k_) {                                        \
        rr[k_] = rs[k_ * 64];                                                  \
        pv[k_] = es[k_ * 64];                                                  \
    }                                                                          \
    _Pragma("unroll")                                                          \
    for (int s_ = 0; s_ < (nn); ++s_) SOIL_STEP(s_, rr[s_], pv[s_], qd);       \
} while (0)

// ---- snow: forcing load + forcing-only recurrence -> rt, raw PET ----------
#define SNOW_HALF(nn, tb, ofs) do {                                            \
    float Pf[15], Tf[15], Ef[15];                                              \
    _Pragma("unroll")                                                          \
    for (int k_ = 0; k_ < (nn); ++k_) {                                        \
        F3 f = xb3[(size_t)((tb) + k_) * HBV_B];                               \
        Pf[k_] = f.x; Tf[k_] = f.y; Ef[k_] = f.z;                              \
    }                                                                          \
    float* rd = &rtS[(ofs)];                                                   \
    float* ed = &petS[(ofs)];                                                  \
    _Pragma("unroll")                                                          \
    for (int s_ = 0; s_ < (nn); ++s_) {                                        \
        float Pm = Pf[s_], Tc = Tf[s_];                                        \
        float rain = (Tc >= parTT) ? Pm : 0.0f;                                \
        SNW += Pm - rain;                                                      \
        float melt = fminf(fmaxf(__builtin_fmaf(parCFMAX, Tc, negCT), 0.0f),   \
                           SNW);                                               \
        MLT += melt; SNW -= melt;                                              \
        float rfz = fminf(fmaxf(__builtin_fmaf(-CFRC, Tc, CFRCTT), 0.0f),      \
                          MLT);                                                \
        SNW += rfz; MLT -= rfz;                                                \
        float tosoil = fmaxf(__builtin_fmaf(-parCWH, SNW, MLT), 0.0f);         \
        MLT -= tosoil;                                                         \
        rd[s_ * 64] = rain + tosoil;                                           \
        ed[s_ * 64] = Ef[s_];                                                  \
    }                                                                          \
} while (0)

// ---- route: LDS -> 15-tap FIR ring -> DPP mean over m -> store ------------
// (tb) is always a multiple of 15, so ring slot == local index s_.
#define ROUTE_HALF(nn, tb, ofs) do {                                           \
    const float* qsrc = &qS[(ofs)];                                            \
    float qq[15];                                                              \
    _Pragma("unroll")                                                          \
    for (int k_ = 0; k_ < (nn); ++k_) qq[k_] = qsrc[k_ * 64];                  \
    _Pragma("unroll")                                                          \
    for (int s_ = 0; s_ < (nn); ++s_) {                                        \
        q[s_] = qq[s_];                                                        \
        float qr = 0.0f;                                                       \
        _Pragma("unroll")                                                      \
        for (int k_ = 0; k_ < 15; ++k_)                                        \
            qr += w[k_] * q[(s_ - k_ + 15) % 15];                              \
        DPP_ADD_ROR(qr, 0x128);                                                \
        DPP_ADD_ROR(qr, 0x124);                                                \
        DPP_ADD_ROR(qr, 0x122);                                                \
        DPP_ADD_ROR(qr, 0x121);                                                \
        if (m == 0) out[(size_t)((tb) + s_) * HBV_B + b] = qr;                 \
    }                                                                          \
} while (0)

__global__ __launch_bounds__(256, 1)
void hbv_smt_kernel(const float* __restrict__ x_phy,   // (2000, 1024, 3)
                    const float* __restrict__ ps,      // (1024, 288)
                    float* __restrict__ out)           // (2000, 1024)
{
    const int lane = (int)threadIdx.x & 63;
    const int wv   = (int)threadIdx.x >> 6;   // 0 soil, 1 route, 2 snow, 3 idle
    const int b    = blockIdx.x * 4 + (lane >> 4);
    const int m    = lane & 15;

    __shared__ float rtS [2 * SBUF];  // snow -> soil : rain+tosoil
    __shared__ float petS[2 * SBUF];  // snow -> soil : raw PET
    __shared__ float qS  [2 * SBUF];  // soil -> route: Qsim
    // +36 KB dynamic LDS at launch pads the group segment past 80 KB so a
    // second block can never co-reside (keeps SIMD0 exclusively soil's).

    const float* __restrict__ pb = ps + (size_t)b * 288;

    if (wv == 0) {
        // --------------------------- SOIL (SIMD0) ---------------------------
        const float parBETA   = 1.0f   + pb[ 0*16 + m] * 5.0f;
        const float parFC     = 50.0f  + pb[ 1*16 + m] * 950.0f;
        const float parK0     = 0.05f  + pb[ 2*16 + m] * 0.85f;
        const float parK1     = 0.01f  + pb[ 3*16 + m] * 0.49f;
        const float parK2     = 0.001f + pb[ 4*16 + m] * 0.199f;
        const float parLP     = 0.2f   + pb[ 5*16 + m] * 0.8f;
        const float parPERC   =          pb[ 6*16 + m] * 10.0f;
        const float parUZL    =          pb[ 7*16 + m] * 100.0f;
        const float parBETAET = 0.3f   + pb[12*16 + m] * 4.7f;
        const float parC      =          pb[13*16 + m];
        const float invFC  = 1.0f / parFC;
        const float K0c    = 1.0f - parK0;
        const float K0UZL  = parK0 * parUZL;
        const float K1c    = 1.0f - parK1;
        const float K2c    = 1.0f - parK2;
        const float nBlogFC    = -parBETA   * __builtin_amdgcn_logf(parFC);
        const float nBEloglpfc = -parBETAET * __builtin_amdgcn_logf(parLP * parFC);

        float SM = HBV_NZ, SUZ = HBV_NZ, SLZ = HBV_NZ;

        __syncthreads();                                  // phase 0
#pragma unroll 1
        for (int sc = 0; sc < 66; ++sc) {                 // phases 1..66
            const int po = (sc & 1) * SBUF + lane;
            SOIL_HALF(15, po);
            SOIL_HALF(15, po + 15 * 64);
            __syncthreads();
        }
        // sc=66 (20 steps, parity 0): phase 67
        SOIL_HALF(15, lane);
        SOIL_HALF(5, lane + 15 * 64);
        __syncthreads();
        __syncthreads();                                  // phase 68
        // 69 barriers.
    } else if (wv == 2) {
        // --------------------------- SNOW (SIMD2) ---------------------------
        const float parTT    = -2.5f + pb[ 8*16 + m] * 5.0f;
        const float parCFMAX = 0.5f  + pb[ 9*16 + m] * 9.5f;
        const float parCFR   =         pb[10*16 + m] * 0.1f;
        const float parCWH   =         pb[11*16 + m] * 0.2f;
        const float CFRC   = parCFR * parCFMAX;
        const float negCT  = -parCFMAX * parTT;
        const float CFRCTT =  CFRC * parTT;
        float SNW = HBV_NZ, MLT = HBV_NZ;
        const F3* __restrict__ xb3 = (const F3*)x_phy + b;

#pragma unroll 1
        for (int sc = 0; sc < 66; ++sc) {                 // phases 0..65
            const int po = (sc & 1) * SBUF + lane;
            SNOW_HALF(15, sc * 30,      po);
            SNOW_HALF(15, sc * 30 + 15, po + 15 * 64);
            __syncthreads();
        }
        // sc=66: phase 66
        SNOW_HALF(15, 1980, lane);
        SNOW_HALF(5, 1995, lane + 15 * 64);
        __syncthreads();
        __syncthreads();                                  // phase 67
        __syncthreads();                                  // phase 68
        // 69 barriers.
    } else if (wv == 1) {
        // --------------------------- ROUTE (SIMD1) --------------------------
        const float rout_a = pb[256 + m]      * 2.9f;
        const float rout_b = pb[256 + 16 + m] * 6.5f;
        // w[k] ∝ t_k^(a-1) exp(-t_k/theta); Gamma/theta^a cancels under
        // normalization; pre-scaled by 1/16 for the mean over m.
        const float aa    = fmaxf(rout_a, 0.0f) + 0.1f;
        const float theta = fmaxf(rout_b, 0.0f) + 0.5f;
        const float am1   = aa - 1.0f;
        const float nit   = -1.4426950408889634f / theta;
        float w[15];
        float wsum = 0.0f;
#pragma unroll
        for (int k = 0; k < 15; ++k) {
            float tk = (float)k + 0.5f;
            float e  = am1 * __builtin_amdgcn_logf(tk) + nit * tk;
            w[k] = __builtin_amdgcn_exp2f(e);
            wsum += w[k];
        }
        const float wscale = 1.0f / (16.0f * wsum);
#pragma unroll
        for (int k = 0; k < 15; ++k) w[k] *= wscale;
        float q[15];
#pragma unroll
        for (int k = 0; k < 15; ++k) q[k] = 0.0f;

        __syncthreads();                                  // phase 0
        __syncthreads();                                  // phase 1
#pragma unroll 1
        for (int sc = 0; sc < 66; ++sc) {                 // phases 2..67
            const int po = (sc & 1) * SBUF + lane;
            ROUTE_HALF(15, sc * 30,      po);
            ROUTE_HALF(15, sc * 30 + 15, po + 15 * 64);
            __syncthreads();
        }
        // sc=66: phase 68
        ROUTE_HALF(15, 1980, lane);
        ROUTE_HALF(5, 1995, lane + 15 * 64);
        __syncthreads();
        // 69 barriers.
    } else {
        // --------------------------- IDLER (SIMD3) --------------------------
#pragma unroll 1
        for (int p = 0; p < 69; ++p) __syncthreads();
    }
}

extern "C" void kernel_launch(void* const* d_in, const int* in_sizes, int n_in,
                              void* d_out, int out_size, void* d_ws, size_t ws_size,
                              hipStream_t stream) {
    const float* x_phy = (const float*)d_in[0];   // (2000,1024,3) fp32
    const float* ps    = (const float*)d_in[1];   // (1024,288)    fp32
    float* out         = (float*)d_out;           // (2000,1024)   fp32

    // 256 blocks x 256 threads (4 waves, 1/SIMD), 1 block/CU (LDS-padded).
    // Wall = 2000 x soil chain (4 trans + 6 VALU, med3 capillary fold).
    // 36 KB dynamic LDS: occupancy clamp only (46 KB static + 36 KB > 80 KB).
    hbv_smt_kernel<<<256, 256, 36 * 1024, stream>>>(x_phy, ps, out);
}

// Round 6
// 221.448 us; speedup vs baseline: 1.0138x; 1.0138x over previous
//
#include <hip/hip_runtime.h>

#define HBV_B  1024
#define HBV_NZ 1e-5f
#define SBUF   (30 * 64)       // one 30-step superchunk buffer (64 lanes)

// ---------------------------------------------------------------------------
// R13 = R11 restored verbatim (best verified: 165.5us steady / 222.1 bench).
// Session ladder: R8 253.6 -> R11 165.5 (solo-SIMD soil + ET clamp fold) ->
// R12 168.9 (med3 fold REGRESSED; reverted here).
// Final model (validated by R9/R11/R12 fits):
//   wall = 2000 x serial soil-chain dep latency on a quiet SIMD
//        = 2000 x [4 trans-dep (~47 cyc each) + ~11 cyc staging/barrier]
//        ~ 199 cyc/step = 166 us.
//   - VALU polys for log2/exp2 do NOT beat the trans unit (R9: +30%).
//   - VALU levels between transcendentals are hidden under trans latency
//     (R12: removing one V level changed nothing on-chain, cost off-chain).
//   - Both soil waves must be on DIFFERENT SIMDs; second wave on the same
//     SIMD costs +105 cyc/step of trans/issue contention (R8 vs R11).
// Structure: 256 blocks x 256 threads, 1 block/CU (LDS pad), one wave/SIMD;
// wv0 soil (solo SIMD0), wv1 route, wv2 snow, wv3 idle.
//  - ET trim: evapfactor = clip01((SM3/(LP*FC))^BETAET) -> ef =
//    clamp01(exp2(BETAET*log2(SM3)+c)) folds the clip into v_exp_f32's
//    output clamp; SM' = max(fma(-PETm, ef, SM3), NZ). Snow passes RAW PET.
//    Chain: 4 trans + 7 VALU.
// Phase machine (69 barriers/wave), superchunks sc=0..66 (sc66 = 20 steps):
//   phase p: snow sc p (p<=66) | soil sc p-1 (1<=p<=67) | route sc p-2
//   (2<=p<=68). Buffer parity = sc&1. Sub-blocks of 15 keep FIR ring aligned.
// ---------------------------------------------------------------------------

struct F3 { float x, y, z; };

#define DPP_ADD_ROR(x, ctrl) do {                                              \
    int _r = __builtin_amdgcn_update_dpp(0, __float_as_int(x),                 \
                                         (ctrl), 0xF, 0xF, true);              \
    (x) += __int_as_float(_r);                                                 \
} while (0)

// ---- soil step: hw trans chain, both exp2 clamps folded (4T + 7V deep) ----
#define SOIL_STEP(s, rt_, pet_, qdst) do {                                     \
    float rt   = (rt_);                                                        \
    float PETm = (pet_);                                                       \
    float CSLZ = parC * SLZ;                                                   \
    float c1   = __builtin_fmaf(-CSLZ, invFC, 1.0f);                           \
    float SMrt = SM + rt;                                                      \
    /* ---- cross-step critical chain ---- */                                  \
    float lSM = __builtin_amdgcn_logf(SM);                                     \
    float esw = __builtin_fmaf(parBETA, lSM, nBlogFC);                         \
    float swr = __builtin_amdgcn_exp2f(esw);                                   \
    float sw  = fminf(fmaxf(swr, 0.0f), 1.0f);   /* -> v_exp clamp mod */      \
    float SM1 = __builtin_fmaf(-rt, sw, SMrt);                                 \
    float SM2 = fminf(SM1, parFC);                                             \
    float SM3 = __builtin_fmaf(SM2, c1, CSLZ);                                 \
    float lS3 = __builtin_amdgcn_logf(SM3);                                    \
    float eef = __builtin_fmaf(parBETAET, lS3, nBEloglpfc);                    \
    float efr = __builtin_amdgcn_exp2f(eef);                                   \
    float ef  = fminf(fmaxf(efr, 0.0f), 1.0f);   /* -> v_exp clamp mod */      \
    SM = fmaxf(__builtin_fmaf(-PETm, ef, SM3), HBV_NZ);                        \
    /* ---- off-chain: SUZ/SLZ/Q ---- */                                       \
    float U_ = __builtin_fmaf(rt, sw, SM1 - SM2);   /* recharge+excess */      \
    float S_ = SUZ + U_;                                                       \
    float P_ = fminf(S_, parPERC);                                             \
    float A_ = S_ - P_;                                                        \
    float B_ = fminf(A_, __builtin_fmaf(K0c, A_, K0UZL));                      \
    SUZ = K1c * B_;                                                            \
    float L_ = SLZ - (SM3 - SM2) + P_;                                         \
    SLZ = K2c * L_;                                                            \
    (qdst)[(s) * 64] = __builtin_fmaf(parK2, L_, A_ - SUZ);                    \
} while (0)

// One 15-or-5-step sub-block: stage LDS -> registers, run steps.
#define SOIL_HALF(nn, ofs) do {                                                \
    const float* rs = &rtS[(ofs)];                                             \
    const float* es = &petS[(ofs)];                                            \
    float* qd = &qS[(ofs)];                                                    \
    float rr[15], pv[15];                                                      \
    _Pragma("unroll")                                                          \
    for (int k_ = 0; k_ < (nn); ++k_) {                                        \
        rr[k_] = rs[k_ * 64];                                                  \
        pv[k_] = es[k_ * 64];                                                  \
    }                                                                          \
    _Pragma("unroll")                                                          \
    for (int s_ = 0; s_ < (nn); ++s_) SOIL_STEP(s_, rr[s_], pv[s_], qd);       \
} while (0)

// ---- snow: forcing load + forcing-only recurrence -> rt, raw PET ----------
#define SNOW_HALF(nn, tb, ofs) do {                                            \
    float Pf[15], Tf[15], Ef[15];                                              \
    _Pragma("unroll")                                                          \
    for (int k_ = 0; k_ < (nn); ++k_) {                                        \
        F3 f = xb3[(size_t)((tb) + k_) * HBV_B];                               \
        Pf[k_] = f.x; Tf[k_] = f.y; Ef[k_] = f.z;                              \
    }                                                                          \
    float* rd = &rtS[(ofs)];                                                   \
    float* ed = &petS[(ofs)];                                                  \
    _Pragma("unroll")                                                          \
    for (int s_ = 0; s_ < (nn); ++s_) {                                        \
        float Pm = Pf[s_], Tc = Tf[s_];                                        \
        float rain = (Tc >= parTT) ? Pm : 0.0f;                                \
        SNW += Pm - rain;                                                      \
        float melt = fminf(fmaxf(__builtin_fmaf(parCFMAX, Tc, negCT), 0.0f),   \
                           SNW);                                               \
        MLT += melt; SNW -= melt;                                              \
        float rfz = fminf(fmaxf(__builtin_fmaf(-CFRC, Tc, CFRCTT), 0.0f),      \
                          MLT);                                                \
        SNW += rfz; MLT -= rfz;                                                \
        float tosoil = fmaxf(__builtin_fmaf(-parCWH, SNW, MLT), 0.0f);         \
        MLT -= tosoil;                                                         \
        rd[s_ * 64] = rain + tosoil;                                           \
        ed[s_ * 64] = Ef[s_];                                                  \
    }                                                                          \
} while (0)

// ---- route: LDS -> 15-tap FIR ring -> DPP mean over m -> store ------------
// (tb) is always a multiple of 15, so ring slot == local index s_.
#define ROUTE_HALF(nn, tb, ofs) do {                                           \
    const float* qsrc = &qS[(ofs)];                                            \
    float qq[15];                                                              \
    _Pragma("unroll")                                                          \
    for (int k_ = 0; k_ < (nn); ++k_) qq[k_] = qsrc[k_ * 64];                  \
    _Pragma("unroll")                                                          \
    for (int s_ = 0; s_ < (nn); ++s_) {                                        \
        q[s_] = qq[s_];                                                        \
        float qr = 0.0f;                                                       \
        _Pragma("unroll")                                                      \
        for (int k_ = 0; k_ < 15; ++k_)                                        \
            qr += w[k_] * q[(s_ - k_ + 15) % 15];                              \
        DPP_ADD_ROR(qr, 0x128);                                                \
        DPP_ADD_ROR(qr, 0x124);                                                \
        DPP_ADD_ROR(qr, 0x122);                                                \
        DPP_ADD_ROR(qr, 0x121);                                                \
        if (m == 0) out[(size_t)((tb) + s_) * HBV_B + b] = qr;                 \
    }                                                                          \
} while (0)

__global__ __launch_bounds__(256, 1)
void hbv_smt_kernel(const float* __restrict__ x_phy,   // (2000, 1024, 3)
                    const float* __restrict__ ps,      // (1024, 288)
                    float* __restrict__ out)           // (2000, 1024)
{
    const int lane = (int)threadIdx.x & 63;
    const int wv   = (int)threadIdx.x >> 6;   // 0 soil, 1 route, 2 snow, 3 idle
    const int b    = blockIdx.x * 4 + (lane >> 4);
    const int m    = lane & 15;

    __shared__ float rtS [2 * SBUF];  // snow -> soil : rain+tosoil
    __shared__ float petS[2 * SBUF];  // snow -> soil : raw PET
    __shared__ float qS  [2 * SBUF];  // soil -> route: Qsim
    // +36 KB dynamic LDS at launch pads the group segment past 80 KB so a
    // second block can never co-reside (keeps SIMD0 exclusively soil's).

    const float* __restrict__ pb = ps + (size_t)b * 288;

    if (wv == 0) {
        // --------------------------- SOIL (SIMD0) ---------------------------
        const float parBETA   = 1.0f   + pb[ 0*16 + m] * 5.0f;
        const float parFC     = 50.0f  + pb[ 1*16 + m] * 950.0f;
        const float parK0     = 0.05f  + pb[ 2*16 + m] * 0.85f;
        const float parK1     = 0.01f  + pb[ 3*16 + m] * 0.49f;
        const float parK2     = 0.001f + pb[ 4*16 + m] * 0.199f;
        const float parLP     = 0.2f   + pb[ 5*16 + m] * 0.8f;
        const float parPERC   =          pb[ 6*16 + m] * 10.0f;
        const float parUZL    =          pb[ 7*16 + m] * 100.0f;
        const float parBETAET = 0.3f   + pb[12*16 + m] * 4.7f;
        const float parC      =          pb[13*16 + m];
        const float invFC  = 1.0f / parFC;
        const float K0c    = 1.0f - parK0;
        const float K0UZL  = parK0 * parUZL;
        const float K1c    = 1.0f - parK1;
        const float K2c    = 1.0f - parK2;
        const float nBlogFC    = -parBETA   * __builtin_amdgcn_logf(parFC);
        const float nBEloglpfc = -parBETAET * __builtin_amdgcn_logf(parLP * parFC);

        float SM = HBV_NZ, SUZ = HBV_NZ, SLZ = HBV_NZ;

        __syncthreads();                                  // phase 0
#pragma unroll 1
        for (int sc = 0; sc < 66; ++sc) {                 // phases 1..66
            const int po = (sc & 1) * SBUF + lane;
            SOIL_HALF(15, po);
            SOIL_HALF(15, po + 15 * 64);
            __syncthreads();
        }
        // sc=66 (20 steps, parity 0): phase 67
        SOIL_HALF(15, lane);
        SOIL_HALF(5, lane + 15 * 64);
        __syncthreads();
        __syncthreads();                                  // phase 68
        // 69 barriers.
    } else if (wv == 2) {
        // --------------------------- SNOW (SIMD2) ---------------------------
        const float parTT    = -2.5f + pb[ 8*16 + m] * 5.0f;
        const float parCFMAX = 0.5f  + pb[ 9*16 + m] * 9.5f;
        const float parCFR   =         pb[10*16 + m] * 0.1f;
        const float parCWH   =         pb[11*16 + m] * 0.2f;
        const float CFRC   = parCFR * parCFMAX;
        const float negCT  = -parCFMAX * parTT;
        const float CFRCTT =  CFRC * parTT;
        float SNW = HBV_NZ, MLT = HBV_NZ;
        const F3* __restrict__ xb3 = (const F3*)x_phy + b;

#pragma unroll 1
        for (int sc = 0; sc < 66; ++sc) {                 // phases 0..65
            const int po = (sc & 1) * SBUF + lane;
            SNOW_HALF(15, sc * 30,      po);
            SNOW_HALF(15, sc * 30 + 15, po + 15 * 64);
            __syncthreads();
        }
        // sc=66: phase 66
        SNOW_HALF(15, 1980, lane);
        SNOW_HALF(5, 1995, lane + 15 * 64);
        __syncthreads();
        __syncthreads();                                  // phase 67
        __syncthreads();                                  // phase 68
        // 69 barriers.
    } else if (wv == 1) {
        // --------------------------- ROUTE (SIMD1) --------------------------
        const float rout_a = pb[256 + m]      * 2.9f;
        const float rout_b = pb[256 + 16 + m] * 6.5f;
        // w[k] ∝ t_k^(a-1) exp(-t_k/theta); Gamma/theta^a cancels under
        // normalization; pre-scaled by 1/16 for the mean over m.
        const float aa    = fmaxf(rout_a, 0.0f) + 0.1f;
        const float theta = fmaxf(rout_b, 0.0f) + 0.5f;
        const float am1   = aa - 1.0f;
        const float nit   = -1.4426950408889634f / theta;
        float w[15];
        float wsum = 0.0f;
#pragma unroll
        for (int k = 0; k < 15; ++k) {
            float tk = (float)k + 0.5f;
            float e  = am1 * __builtin_amdgcn_logf(tk) + nit * tk;
            w[k] = __builtin_amdgcn_exp2f(e);
            wsum += w[k];
        }
        const float wscale = 1.0f / (16.0f * wsum);
#pragma unroll
        for (int k = 0; k < 15; ++k) w[k] *= wscale;
        float q[15];
#pragma unroll
        for (int k = 0; k < 15; ++k) q[k] = 0.0f;

        __syncthreads();                                  // phase 0
        __syncthreads();                                  // phase 1
#pragma unroll 1
        for (int sc = 0; sc < 66; ++sc) {                 // phases 2..67
            const int po = (sc & 1) * SBUF + lane;
            ROUTE_HALF(15, sc * 30,      po);
            ROUTE_HALF(15, sc * 30 + 15, po + 15 * 64);
            __syncthreads();
        }
        // sc=66: phase 68
        ROUTE_HALF(15, 1980, lane);
        ROUTE_HALF(5, 1995, lane + 15 * 64);
        __syncthreads();
        // 69 barriers.
    } else {
        // --------------------------- IDLER (SIMD3) --------------------------
#pragma unroll 1
        for (int p = 0; p < 69; ++p) __syncthreads();
    }
}

extern "C" void kernel_launch(void* const* d_in, const int* in_sizes, int n_in,
                              void* d_out, int out_size, void* d_ws, size_t ws_size,
                              hipStream_t stream) {
    const float* x_phy = (const float*)d_in[0];   // (2000,1024,3) fp32
    const float* ps    = (const float*)d_in[1];   // (1024,288)    fp32
    float* out         = (float*)d_out;           // (2000,1024)   fp32

    // 256 blocks x 256 threads (4 waves, 1/SIMD), 1 block/CU (LDS-padded).
    // Wall = 2000 x soil chain (4 trans + 7 VALU); soil wave owns SIMD0.
    // 36 KB dynamic LDS: occupancy clamp only (46 KB static + 36 KB > 80 KB).
    hbv_smt_kernel<<<256, 256, 36 * 1024, stream>>>(x_phy, ps, out);
}